// Round 14
// baseline (258.631 us; speedup 1.0000x reference)
//
#include <hip/hip_runtime.h>
#include <hip/hip_bf16.h>
#include <cstdint>
#include <cstddef>

// Shapes (fixed): B=4, C=512, H=W=64, N=4096, td=512. Inputs/outputs fp32
// (proven in R4). Compute in bf16 MFMA with fp32 accumulation.
//   x (4,512,4096) | w_qkv (1536,512) | w_dw (1536,25) | w_pw (1536,8) |
//   w_proj (512,1024) | out (4,512,4096) fp32
//
// ws layout (bytes; total ~114.6 MiB):
//   w_qkv_bf  1,572,864 | w_proj_bf 1,048,576 | vk 147,456 |
//   x_t (4,4096,512) bf16 16,777,216 | qkv 50,331,648 | agg 50,331,648
//
// attn is stored head-chunk-transposed over the dead v-rows of qkv/agg:
// chunk(b,h) = 4096 n x 8 d, d contiguous -> proj GEMM B^T staging is
// lane-contiguous for global_load_lds.

typedef __hip_bfloat16 bf16;
typedef __attribute__((ext_vector_type(8))) short short8;
typedef __attribute__((ext_vector_type(4))) float f32x4;

__device__ __forceinline__ float b2f(bf16 v) { return __bfloat162float(v); }
__device__ __forceinline__ bf16 f2b(float v) { return __float2bfloat16(v); }
__device__ __forceinline__ float us2f(unsigned short u) {
    return __uint_as_float(((unsigned)u) << 16);
}

// bf16-pair dot: acc += p.lo*w.lo + p.hi*w.hi (f32 accumulate).
// VOP3P v_dot2_f32_bf16 when available; scalar fallback otherwise.
__device__ __forceinline__ float dot2bf(unsigned p, unsigned wp, float acc) {
#if __has_builtin(__builtin_amdgcn_fdot2_f32_bf16)
    typedef __attribute__((ext_vector_type(2))) __bf16 bf16x2;
    return __builtin_amdgcn_fdot2_f32_bf16(
        __builtin_bit_cast(bf16x2, p), __builtin_bit_cast(bf16x2, wp),
        acc, false);
#else
    return acc
        + us2f((unsigned short)(p & 0xffffu))  * us2f((unsigned short)(wp & 0xffffu))
        + us2f((unsigned short)(p >> 16))      * us2f((unsigned short)(wp >> 16));
#endif
}

__device__ __forceinline__ void async16(void* lds_base, const void* gaddr) {
    // dest = lds_base (wave-uniform) + lane*16; per-lane global address.
    __builtin_amdgcn_global_load_lds(
        (const __attribute__((address_space(1))) unsigned int*)gaddr,
        (__attribute__((address_space(3))) unsigned int*)lds_base,
        16, 0, 0);
}

// ---- weight fp32 -> bf16 ----
__global__ __launch_bounds__(256) void convert_kernel(
    const float* __restrict__ src, bf16* __restrict__ dst, int n)
{
    int i = blockIdx.x * 256 + threadIdx.x;
    if (i < n) dst[i] = f2b(src[i]);
}

// ---- x (4,512,4096) fp32 -> x_t (4,4096,512) bf16 ----
__global__ __launch_bounds__(256) void transpose_x_kernel(
    const float* __restrict__ x, bf16* __restrict__ x_t)
{
    __shared__ bf16 tile[32][33];
    const int b = blockIdx.z;
    const int c0 = blockIdx.y * 32;
    const int n0 = blockIdx.x * 32;
    const int tx = threadIdx.x & 31, ty = threadIdx.x >> 5;  // 32x8
    #pragma unroll
    for (int i = 0; i < 32; i += 8)
        tile[ty + i][tx] = f2b(x[((size_t)b * 512 + c0 + ty + i) * 4096 + n0 + tx]);
    __syncthreads();
    #pragma unroll
    for (int i = 0; i < 32; i += 8)
        x_t[((size_t)b * 4096 + n0 + ty + i) * 512 + c0 + tx] = tile[tx][ty + i];
}

// ---- MFMA GEMM v10: 64x128 tile, TRIPLE-buffered, counted vmcnt ----
// R13 lesson: v9's distance-1 prefetch + vmcnt(0) waits on loads issued
// THIS iteration -> full latency exposed (3300 cy/iter, MfmaUtil 14%).
// v10: prefetch distance 2. Iter t: issue stage(t+2), wait vmcnt(6)
// (drains only tile t's loads, issued a full iteration ago), barrier,
// compute buf[t%3], barrier (readers-done fence before restage).
// BM=64 -> LDS 3x12KB=36KB -> 4 blocks/CU; proj grid 1024 (16 waves/CU,
// 2x v9), qkv grid 3072.
// Wave w (of 4): wm=(w>>1)*32, wn=(w&1)*64; per-wave out 32x64, acc[2][4].
// Per-wave stage: 1x A-chunk + 2x B-chunks = 3 async16 -> vmcnt counts
// in units of 3 per stage.
// PROJ=false: C[b](1536x4096) bf16 = A(1536x512) * x_t[b]^T ; K=512
// PROJ=true:  out[b](512x4096) f32 = A(512x1024) * attn[b] + x[b] ; K=1024
template <bool PROJ>
__global__ __launch_bounds__(256) void mfma_gemm_kernel(
    const bf16* __restrict__ A, const bf16* __restrict__ xt_or_qkv,
    const bf16* __restrict__ agg, const float* __restrict__ X,
    void* __restrict__ Cout, int M, int K)
{
    constexpr int N = 4096;
    constexpr int BM = 64;
    const int b = blockIdx.z;
    const int m_blk = blockIdx.y * BM;
    const int n_blk = blockIdx.x * 128;

    __shared__ short As[3][BM * 32];    // 4 KB / buf
    __shared__ short Bs[3][128 * 32];   // 8 KB / buf

    const int tid = threadIdx.x;
    const int lane = tid & 63, wave = tid >> 6;
    const int wm = (wave >> 1) * 32, wn = (wave & 1) * 64;
    const int fm = lane & 15, fq = lane >> 4;

    f32x4 acc[2][4] = {};

    const short* Ag = (const short*)A;
    const short* Btg = PROJ ? nullptr
        : (const short*)(xt_or_qkv + (size_t)b * N * 512);  // x_t[b]

    // stage one 32-k tile into buffer `buf`: 3 async16 per wave
    auto stage = [&](int buf, int k0) {
        {   // A: 4 chunks of 16 rows; wave does chunk `wave`
            int row = m_blk + wave * 16 + (lane >> 2);
            int col = k0 + (lane & 3) * 8;
            async16(&As[buf][wave * 512], Ag + (size_t)row * K + col);
        }
        #pragma unroll
        for (int t0 = 0; t0 < 2; ++t0) {   // B: 8 chunks; wave does {w, w+4}
            int t = wave + t0 * 4;
            int n = n_blk + t * 16 + (lane >> 2);
            if (!PROJ) {
                int col = k0 + (lane & 3) * 8;
                async16(&Bs[buf][t * 512], Btg + (size_t)n * 512 + col);
            } else {
                int h = (k0 >> 3) + (lane & 3);      // 4 heads per k-tile
                const bf16* chunk = (h < 64 ? xt_or_qkv : agg) +
                    ((size_t)b * 1536 + (size_t)(h & 63) * 24 + 16) * 4096;
                async16(&Bs[buf][t * 512], chunk + (size_t)n * 8);
            }
        }
    };

    const int nt = K >> 5;
    stage(0, 0);
    stage(1, 32);

    int cb = 0;          // compute buffer (t % 3)
    int sb = 2;          // stage buffer ((t+2) % 3)
    for (int t = 0; t < nt; ++t) {
        if (t + 2 < nt) {
            stage(sb, (t + 2) * 32);
            asm volatile("s_waitcnt vmcnt(6)" ::: "memory");   // drain tile t
        } else if (t + 1 < nt) {
            asm volatile("s_waitcnt vmcnt(3)" ::: "memory");
        } else {
            asm volatile("s_waitcnt vmcnt(0)" ::: "memory");
        }
        __builtin_amdgcn_s_barrier();      // buf[cb] ready for all waves

        short8 af[2], bfv[4];
        #pragma unroll
        for (int i = 0; i < 2; ++i)
            af[i] = *(const short8*)&As[cb][(wm + i * 16 + fm) * 32 + fq * 8];
        #pragma unroll
        for (int j = 0; j < 4; ++j)
            bfv[j] = *(const short8*)&Bs[cb][(wn + j * 16 + fm) * 32 + fq * 8];
        #pragma unroll
        for (int i = 0; i < 2; ++i)
            #pragma unroll
            for (int j = 0; j < 4; ++j)
                acc[i][j] = __builtin_amdgcn_mfma_f32_16x16x32_bf16(
                    af[i], bfv[j], acc[i][j], 0, 0, 0);

        __builtin_amdgcn_s_barrier();      // readers done before restage
        cb = (cb == 2) ? 0 : cb + 1;
        sb = (sb == 2) ? 0 : sb + 1;
    }

    // epilogue: C/D layout col=lane&15, row=(lane>>4)*4+reg
    if (!PROJ) {
        bf16* Cb = (bf16*)Cout + (size_t)b * M * N;
        #pragma unroll
        for (int i = 0; i < 2; ++i)
            #pragma unroll
            for (int j = 0; j < 4; ++j) {
                int n = n_blk + wn + j * 16 + fm;
                #pragma unroll
                for (int r = 0; r < 4; ++r) {
                    int m = m_blk + wm + i * 16 + fq * 4 + r;
                    Cb[(size_t)m * N + n] = f2b(acc[i][j][r]);
                }
            }
    } else {
        float* Ob = (float*)Cout + (size_t)b * M * N;
        const float* Xb = X + (size_t)b * M * N;
        #pragma unroll
        for (int i = 0; i < 2; ++i)
            #pragma unroll
            for (int j = 0; j < 4; ++j) {
                int n = n_blk + wn + j * 16 + fm;
                #pragma unroll
                for (int r = 0; r < 4; ++r) {
                    int m = m_blk + wm + i * 16 + fq * 4 + r;
                    size_t off = (size_t)m * N + n;
                    Ob[off] = acc[i][j][r] + Xb[off];
                }
            }
    }
}

// ---- fused depthwise 5x5 (pad 2) + grouped pointwise (8->8), v7 ----
// packed-bf16 dot2 with edge words fetched by CROSS-LANE SHUFFLE:
// lo word (cols 8sx-2,-1) == lane-1's mid.w, hi word == lane+1's mid.x.
// 40 VMEM instr/thread; boundary lanes masked by lo_keep/hi_keep.
__global__ __launch_bounds__(256) void dwpw_kernel(
    const bf16* __restrict__ qkv, const float* __restrict__ w_dw,
    const float* __restrict__ w_pw, bf16* __restrict__ agg)
{
    const int bg = blockIdx.y;           // b*192 + g
    const int b = bg / 192;
    const int g = bg - b * 192;
    const int y0 = blockIdx.x * 32;      // output rows [y0, y0+32)

    __shared__ unsigned s_wdwp[8][16];   // packed bf16 weight pairs
    __shared__ float s_wpw[8][8];

    const int tid = threadIdx.x;

    // pack dw weights: per (c, i, part): pair (w[i*5+2p], w[i*5+2p+1]) ; part2 = (w4, 0)
    if (tid < 120) {
        int c = tid / 15, s = tid - c * 15;
        int i = s / 3, p = s - i * 3;
        int idx = i * 5 + p * 2;
        float w0 = w_dw[(size_t)(g * 8 + c) * 25 + idx];
        float w1 = (p < 2) ? w_dw[(size_t)(g * 8 + c) * 25 + idx + 1] : 0.f;
        unsigned u0 = __builtin_bit_cast(unsigned short, f2b(w0));
        unsigned u1 = __builtin_bit_cast(unsigned short, f2b(w1));
        s_wdwp[c][s] = u0 | (u1 << 16);
    }
    if (tid < 64)
        s_wpw[tid >> 3][tid & 7] = w_pw[(size_t)(g * 8 + (tid >> 3)) * 8 + (tid & 7)];
    __syncthreads();

    const int py = tid >> 3;             // 0..31
    const int sx = tid & 7;              // 0..7 (8-col strip)
    const int yq = y0 + py;
    const size_t chan_base = ((size_t)b * 1536 + g * 8) * 4096;

    const unsigned lo_keep = (sx > 0) ? 0xFFFFFFFFu : 0u;
    const unsigned hi_keep = (sx < 7) ? 0xFFFFFFFFu : 0u;

    float dwv[8][8];
    #pragma unroll
    for (int c = 0; c < 8; ++c) {
        unsigned wpq[16];
        #pragma unroll
        for (int q = 0; q < 4; ++q)
            *(uint4*)&wpq[q * 4] = *(const uint4*)&s_wdwp[c][q * 4];

        const char* cbase = (const char*)(qkv + chan_base + (size_t)c * 4096);
        float a[8] = {};
        #pragma unroll
        for (int i = 0; i < 5; ++i) {
            const int y = yq + i - 2;
            const bool row_ok = ((unsigned)y < 64u);
            const int yc = row_ok ? y : 0;             // safe address
            const char* rowp = cbase + yc * 128;       // 128 B per row
            uint4 mid = *(const uint4*)(rowp + 16 * sx);
            const unsigned m = row_ok ? 0xFFFFFFFFu : 0u;

            // edge words from neighbor lanes' registers (same py, same y)
            unsigned lo = (unsigned)__shfl_up((int)mid.w, 1, 64);
            unsigned hi = (unsigned)__shfl_down((int)mid.x, 1, 64);

            // packed bf16 words W0..W5 = elems (e0,e1)..(e10,e11), e_k = col 8sx-2+k
            unsigned W0 = lo & m & lo_keep;
            unsigned W1 = mid.x & m, W2 = mid.y & m;
            unsigned W3 = mid.z & m, W4 = mid.w & m;
            unsigned W5 = hi & m & hi_keep;
            // shifted pairs S_k = (e_{2k+1}, e_{2k+2})
            unsigned S0 = __builtin_amdgcn_alignbit(W1, W0, 16);
            unsigned S1 = __builtin_amdgcn_alignbit(W2, W1, 16);
            unsigned S2 = __builtin_amdgcn_alignbit(W3, W2, 16);
            unsigned S3 = __builtin_amdgcn_alignbit(W4, W3, 16);
            unsigned S4 = __builtin_amdgcn_alignbit(W5, W4, 16);
            unsigned S5 = W5 >> 16;                    // (e11, 0)

            unsigned w01 = wpq[i * 3], w23 = wpq[i * 3 + 1], w4z = wpq[i * 3 + 2];
            // even x: pairs W[x/2], W[x/2+1], W[x/2+2]
            a[0] = dot2bf(W0, w01, dot2bf(W1, w23, dot2bf(W2, w4z, a[0])));
            a[2] = dot2bf(W1, w01, dot2bf(W2, w23, dot2bf(W3, w4z, a[2])));
            a[4] = dot2bf(W2, w01, dot2bf(W3, w23, dot2bf(W4, w4z, a[4])));
            a[6] = dot2bf(W3, w01, dot2bf(W4, w23, dot2bf(W5, w4z, a[6])));
            // odd x: pairs S[(x-1)/2], S[(x+1)/2], S[(x+3)/2]
            a[1] = dot2bf(S0, w01, dot2bf(S1, w23, dot2bf(S2, w4z, a[1])));
            a[3] = dot2bf(S1, w01, dot2bf(S2, w23, dot2bf(S3, w4z, a[3])));
            a[5] = dot2bf(S2, w01, dot2bf(S3, w23, dot2bf(S4, w4z, a[5])));
            a[7] = dot2bf(S3, w01, dot2bf(S4, w23, dot2bf(S5, w4z, a[7])));
        }
        #pragma unroll
        for (int x = 0; x < 8; ++x) dwv[c][x] = a[x];
    }

    // grouped pointwise 8->8 + bf16 pack/store (16B per channel, coalesced)
    const size_t out_pix = (size_t)yq * 64 + 8 * sx;
    #pragma unroll
    for (int o = 0; o < 8; ++o) {
        float wv[8];
        *(float4*)&wv[0] = *(const float4*)&s_wpw[o][0];
        *(float4*)&wv[4] = *(const float4*)&s_wpw[o][4];
        float s[8] = {};
        #pragma unroll
        for (int i = 0; i < 8; ++i)
            #pragma unroll
            for (int x = 0; x < 8; ++x) s[x] += dwv[i][x] * wv[i];
        union { bf16 hv[8]; uint4 u; } pk;
        #pragma unroll
        for (int x = 0; x < 8; ++x) pk.hv[x] = f2b(s[x]);
        *(uint4*)(agg + chan_base + (size_t)o * 4096 + out_pix) = pk.u;
    }
}

// ---- vk[bh,d,e] = sum_n v[d,n]*relu(k[e,n]); row d=8 = sum relu(k) ----
// v2: 512-thr blocks, one 8-n chunk per thread, short8 (16B) loads:
// 32 vector loads/thread vs 256 scalar 2B loads (G13).
__global__ __launch_bounds__(512) void vk_kernel(
    const bf16* __restrict__ qkv, const bf16* __restrict__ agg,
    float* __restrict__ vk)
{
    const int bh = blockIdx.x;   // 0..511
    const int b = bh >> 7;
    const int h = bh & 127;
    const bf16* base = (h < 64)
        ? (qkv + ((size_t)b * 1536 + h * 24) * 4096)
        : (agg + ((size_t)b * 1536 + (h - 64) * 24) * 4096);

    const int tid = threadIdx.x;
    const int n0 = tid * 8;      // 512 threads x 8 = 4096

    short8 kr[8], vr[8];
    #pragma unroll
    for (int e = 0; e < 8; ++e)
        kr[e] = *(const short8*)&base[(size_t)(8 + e) * 4096 + n0];
    #pragma unroll
    for (int d = 0; d < 8; ++d)
        vr[d] = *(const short8*)&base[(size_t)(16 + d) * 4096 + n0];

    float acc[9][8] = {};
    #pragma unroll
    for (int t = 0; t < 8; ++t) {
        float kt[8], vt[8];
        #pragma unroll
        for (int e = 0; e < 8; ++e)
            kt[e] = fmaxf(us2f((unsigned short)kr[e][t]), 0.f);
        #pragma unroll
        for (int d = 0; d < 8; ++d)
            vt[d] = us2f((unsigned short)vr[d][t]);
        #pragma unroll
        for (int d = 0; d < 8; ++d)
            #pragma unroll
            for (int e = 0; e < 8; ++e)
                acc[d][e] += vt[d] * kt[e];
        #pragma unroll
        for (int e = 0; e < 8; ++e) acc[8][e] += kt[e];
    }

    __shared__ float red[8][72];
    const int lane = tid & 63, wave = tid >> 6;
    #pragma unroll
    for (int d = 0; d < 9; ++d) {
        #pragma unroll
        for (int e = 0; e < 8; ++e) {
            float v = acc[d][e];
            #pragma unroll
            for (int off = 32; off > 0; off >>= 1) v += __shfl_down(v, off, 64);
            if (lane == 0) red[wave][d * 8 + e] = v;
        }
    }
    __syncthreads();
    if (tid < 72) {
        float v = 0.f;
        #pragma unroll
        for (int w = 0; w < 8; ++w) v += red[w][tid];
        vk[(size_t)bh * 72 + tid] = v;
    }
}

// ---- attn: head-chunk-transposed write over dead v-rows ----
// v2: 8-n chunk per thread, short8 q loads (8 x 16B vs 64 x 2B).
// chunk(b,h)[n][d] at (base + 16*4096) + n*8 + d
__global__ __launch_bounds__(256) void attn_out_kernel(
    bf16* __restrict__ qkv, bf16* __restrict__ agg,
    const float* __restrict__ vk)
{
    const int b = blockIdx.z;
    const int h = blockIdx.y;
    const int n0 = (blockIdx.x * 256 + threadIdx.x) * 8;
    bf16* base = (h < 64)
        ? (qkv + ((size_t)b * 1536 + h * 24) * 4096)
        : (agg + ((size_t)b * 1536 + (h - 64) * 24) * 4096);

    __shared__ float s_vk[72];
    if (threadIdx.x < 72)
        s_vk[threadIdx.x] = vk[((size_t)b * 128 + h) * 72 + threadIdx.x];
    __syncthreads();

    short8 qr[8];
    #pragma unroll
    for (int e = 0; e < 8; ++e)
        qr[e] = *(const short8*)&base[(size_t)e * 4096 + n0];

    char* outp = (char*)(base + (size_t)16 * 4096) + (size_t)n0 * 16;
    #pragma unroll
    for (int t = 0; t < 8; ++t) {
        float q[8];
        #pragma unroll
        for (int e = 0; e < 8; ++e)
            q[e] = fmaxf(us2f((unsigned short)qr[e][t]), 0.f);

        float o[9];
        #pragma unroll
        for (int d = 0; d < 9; ++d) {
            float s = 0.f;
            #pragma unroll
            for (int e = 0; e < 8; ++e) s += s_vk[d * 8 + e] * q[e];
            o[d] = s;
        }
        const float denom = o[8] + 1e-15f;

        union { bf16 hv[8]; uint4 u; } pk;
        #pragma unroll
        for (int d = 0; d < 8; ++d) pk.hv[d] = f2b(o[d] / denom);
        *(uint4*)(outp + (size_t)t * 16) = pk.u;
    }
}

extern "C" void kernel_launch(void* const* d_in, const int* in_sizes, int n_in,
                              void* d_out, int out_size, void* d_ws, size_t ws_size,
                              hipStream_t stream) {
    const float* x      = (const float*)d_in[0];
    const float* w_qkv  = (const float*)d_in[1];
    const float* w_dw   = (const float*)d_in[2];
    const float* w_pw   = (const float*)d_in[3];
    const float* w_proj = (const float*)d_in[4];

    char* ws = (char*)d_ws;
    bf16* w_qkv_bf  = (bf16*)ws;                               // 1,572,864 B
    bf16* w_proj_bf = (bf16*)(ws + 1572864);                   // 1,048,576 B
    float* vkbf     = (float*)(ws + 1572864 + 1048576);        //   147,456 B
    bf16* x_t       = (bf16*)(ws + 1572864 + 1048576 + 147456);          // 16 MiB
    bf16* qkv       = x_t + (size_t)4 * 4096 * 512;            // 48 MiB
    bf16* agg       = qkv + (size_t)4 * 1536 * 4096;           // 48 MiB

    // 0. weight conversion + x transpose
    convert_kernel<<<3072, 256, 0, stream>>>(w_qkv, w_qkv_bf, 786432);
    convert_kernel<<<2048, 256, 0, stream>>>(w_proj, w_proj_bf, 524288);
    transpose_x_kernel<<<dim3(128, 16, 4), 256, 0, stream>>>(x, x_t);

    // 1. qkv = w_qkv (1536x512) @ x[b]  (64x128 triple-buffer MFMA v10)
    mfma_gemm_kernel<false><<<dim3(32, 24, 4), 256, 0, stream>>>(
        w_qkv_bf, x_t, nullptr, nullptr, qkv, 1536, 512);

    // 2. agg = grouped-PW(DW5x5(qkv)) — shfl-edge dot2 v7
    dwpw_kernel<<<dim3(2, 768), 256, 0, stream>>>(qkv, w_dw, w_pw, agg);

    // 3. vk per (b, head) — vectorized v2
    vk_kernel<<<dim3(512), 512, 0, stream>>>(qkv, agg, vkbf);

    // 4. attn (normalized), head-chunk-transposed — vectorized v2
    attn_out_kernel<<<dim3(2, 128, 4), 256, 0, stream>>>(qkv, agg, vkbf);

    // 5. out = x + w_proj (512x1024) @ attn[b]  (64x128 triple-buffer MFMA v10)
    mfma_gemm_kernel<true><<<dim3(32, 8, 4), 256, 0, stream>>>(
        w_proj_bf, qkv, agg, x, d_out, 512, 1024);
}

// Round 16
// 250.458 us; speedup vs baseline: 1.0326x; 1.0326x over previous
//
#include <hip/hip_runtime.h>
#include <hip/hip_bf16.h>
#include <cstdint>
#include <cstddef>

// Shapes (fixed): B=4, C=512, H=W=64, N=4096, td=512. Inputs/outputs fp32
// (proven in R4). Compute in bf16 MFMA with fp32 accumulation.
//   x (4,512,4096) | w_qkv (1536,512) | w_dw (1536,25) | w_pw (1536,8) |
//   w_proj (512,1024) | out (4,512,4096) fp32
//
// ws layout (bytes; total ~114.6 MiB):
//   w_qkv_bf  1,572,864 | w_proj_bf 1,048,576 | vk 147,456 |
//   x_t (4,4096,512) bf16 16,777,216 | qkv 50,331,648 | agg 50,331,648
//
// attn is stored head-chunk-transposed over the dead v-rows of qkv/agg:
// chunk(b,h) = 4096 n x 8 d, d contiguous -> proj GEMM B^T staging is
// lane-contiguous for global_load_lds.

typedef __hip_bfloat16 bf16;
typedef __attribute__((ext_vector_type(8))) short short8;
typedef __attribute__((ext_vector_type(4))) float f32x4;

__device__ __forceinline__ float b2f(bf16 v) { return __bfloat162float(v); }
__device__ __forceinline__ bf16 f2b(float v) { return __float2bfloat16(v); }
__device__ __forceinline__ float us2f(unsigned short u) {
    return __uint_as_float(((unsigned)u) << 16);
}

// bf16-pair dot: acc += p.lo*w.lo + p.hi*w.hi (f32 accumulate).
// VOP3P v_dot2_f32_bf16 when available; scalar fallback otherwise.
__device__ __forceinline__ float dot2bf(unsigned p, unsigned wp, float acc) {
#if __has_builtin(__builtin_amdgcn_fdot2_f32_bf16)
    typedef __attribute__((ext_vector_type(2))) __bf16 bf16x2;
    return __builtin_amdgcn_fdot2_f32_bf16(
        __builtin_bit_cast(bf16x2, p), __builtin_bit_cast(bf16x2, wp),
        acc, false);
#else
    return acc
        + us2f((unsigned short)(p & 0xffffu))  * us2f((unsigned short)(wp & 0xffffu))
        + us2f((unsigned short)(p >> 16))      * us2f((unsigned short)(wp >> 16));
#endif
}

__device__ __forceinline__ void async16(void* lds_base, const void* gaddr) {
    // dest = lds_base (wave-uniform) + lane*16; per-lane global address.
    __builtin_amdgcn_global_load_lds(
        (const __attribute__((address_space(1))) unsigned int*)gaddr,
        (__attribute__((address_space(3))) unsigned int*)lds_base,
        16, 0, 0);
}

// ---- weight fp32 -> bf16 ----
__global__ __launch_bounds__(256) void convert_kernel(
    const float* __restrict__ src, bf16* __restrict__ dst, int n)
{
    int i = blockIdx.x * 256 + threadIdx.x;
    if (i < n) dst[i] = f2b(src[i]);
}

// ---- x (4,512,4096) fp32 -> x_t (4,4096,512) bf16 ----
__global__ __launch_bounds__(256) void transpose_x_kernel(
    const float* __restrict__ x, bf16* __restrict__ x_t)
{
    __shared__ bf16 tile[32][33];
    const int b = blockIdx.z;
    const int c0 = blockIdx.y * 32;
    const int n0 = blockIdx.x * 32;
    const int tx = threadIdx.x & 31, ty = threadIdx.x >> 5;  // 32x8
    #pragma unroll
    for (int i = 0; i < 32; i += 8)
        tile[ty + i][tx] = f2b(x[((size_t)b * 512 + c0 + ty + i) * 4096 + n0 + tx]);
    __syncthreads();
    #pragma unroll
    for (int i = 0; i < 32; i += 8)
        x_t[((size_t)b * 4096 + n0 + ty + i) * 512 + c0 + tx] = tile[tx][ty + i];
}

// ---- MFMA GEMM v11: 128x128 tile; per-GEMM pipeline depth ----
// R13: v9 2-buf distance-1 => proj 43.8 (wait covers only own-iter MFMAs).
// R14: v10 BM=64 + 2 barriers + dist-2 => qkv REGRESSED (extra staging +
// barrier overheads). v11 keeps v9's tile/staging exactly and deepens the
// pipeline only where it's free:
//   qkv  (5 blocks/CU): NBUF=2, D=1 — TLP already hides latency.
//   proj (grid-capped 2 blocks/CU): NBUF=4 (64 KB is free), D=2, ONE
//   barrier/iter:  wait vmcnt(4) [drains tile t, issued 2 iters ago,
//   leaves t+1 in flight] -> barrier -> stage(t+2) -> compute(t).
//   Buffer-reuse race is barrier-fenced: buf (t+2)%4 was read at t-2,
//   and every wave passed barrier-t only after compute(t-1).
// PROJ=false: C[b](1536x4096) bf16 = A(1536x512) * x_t[b]^T ; K=512
// PROJ=true:  out[b](512x4096) f32 = A(512x1024) * attn[b] + x[b] ; K=1024
template <bool PROJ>
__global__ __launch_bounds__(256) void mfma_gemm_kernel(
    const bf16* __restrict__ A, const bf16* __restrict__ xt_or_qkv,
    const bf16* __restrict__ agg, const float* __restrict__ X,
    void* __restrict__ Cout, int M, int K)
{
    constexpr int N = 4096;
    constexpr int NBUF = PROJ ? 4 : 2;   // proj: 64 KB LDS (grid-capped 2/CU)
    constexpr int D    = PROJ ? 2 : 1;   // prefetch distance
    const int b = blockIdx.z;
    const int m_blk = blockIdx.y * 128;
    const int n_blk = blockIdx.x * 128;

    __shared__ short As[NBUF][128 * 32];   // 8 KB / buf
    __shared__ short Bs[NBUF][128 * 32];   // 8 KB / buf

    const int tid = threadIdx.x;
    const int lane = tid & 63, wave = tid >> 6;
    const int wm = (wave >> 1) * 64, wn = (wave & 1) * 64;
    const int fm = lane & 15, fq = lane >> 4;

    f32x4 acc[4][4] = {};

    const short* Ag = (const short*)A;
    const short* Btg = PROJ ? nullptr
        : (const short*)(xt_or_qkv + (size_t)b * N * 512);  // x_t[b]

    // stage one 32-k tile into buffer `buf` (4 async16 per wave)
    auto stage = [&](int buf, int k0) {
        #pragma unroll
        for (int t0 = 0; t0 < 2; ++t0) {
            int t = wave + t0 * 4;
            int row = m_blk + t * 16 + (lane >> 2);
            int col = k0 + (lane & 3) * 8;
            async16(&As[buf][t * 512], Ag + (size_t)row * K + col);
        }
        #pragma unroll
        for (int t0 = 0; t0 < 2; ++t0) {
            int t = wave + t0 * 4;
            int n = n_blk + t * 16 + (lane >> 2);
            if (!PROJ) {
                int col = k0 + (lane & 3) * 8;
                async16(&Bs[buf][t * 512], Btg + (size_t)n * 512 + col);
            } else {
                int h = (k0 >> 3) + (lane & 3);      // 4 heads per k-tile
                const bf16* chunk = (h < 64 ? xt_or_qkv : agg) +
                    ((size_t)b * 1536 + (size_t)(h & 63) * 24 + 16) * 4096;
                async16(&Bs[buf][t * 512], chunk + (size_t)n * 8);
            }
        }
    };

    const int nt = K >> 5;
    stage(0, 0);
    if (D == 2 && nt > 1) stage(1, 32);

    for (int t = 0; t < nt; ++t) {
        // drain tile t's 4 loads; with D=2 leave tile t+1's 4 in flight
        if (D == 2 && t < nt - 1)
            asm volatile("s_waitcnt vmcnt(4)" ::: "memory");
        else
            asm volatile("s_waitcnt vmcnt(0)" ::: "memory");
        __builtin_amdgcn_s_barrier();    // buf[t % NBUF] ready for all waves
                                         // + all waves done with buf (t+D)%NBUF
        if (t + D < nt) stage((t + D) & (NBUF - 1), (t + D) * 32);

        const int cb = t & (NBUF - 1);
        short8 af[4], bfv[4];
        #pragma unroll
        for (int i = 0; i < 4; ++i)
            af[i] = *(const short8*)&As[cb][(wm + i * 16 + fm) * 32 + fq * 8];
        #pragma unroll
        for (int j = 0; j < 4; ++j)
            bfv[j] = *(const short8*)&Bs[cb][(wn + j * 16 + fm) * 32 + fq * 8];
        #pragma unroll
        for (int i = 0; i < 4; ++i)
            #pragma unroll
            for (int j = 0; j < 4; ++j)
                acc[i][j] = __builtin_amdgcn_mfma_f32_16x16x32_bf16(
                    af[i], bfv[j], acc[i][j], 0, 0, 0);
    }

    // epilogue: C/D layout col=lane&15, row=(lane>>4)*4+reg
    if (!PROJ) {
        bf16* Cb = (bf16*)Cout + (size_t)b * M * N;
        #pragma unroll
        for (int i = 0; i < 4; ++i)
            #pragma unroll
            for (int j = 0; j < 4; ++j) {
                int n = n_blk + wn + j * 16 + fm;
                #pragma unroll
                for (int r = 0; r < 4; ++r) {
                    int m = m_blk + wm + i * 16 + fq * 4 + r;
                    Cb[(size_t)m * N + n] = f2b(acc[i][j][r]);
                }
            }
    } else {
        float* Ob = (float*)Cout + (size_t)b * M * N;
        const float* Xb = X + (size_t)b * M * N;
        #pragma unroll
        for (int i = 0; i < 4; ++i)
            #pragma unroll
            for (int j = 0; j < 4; ++j) {
                int n = n_blk + wn + j * 16 + fm;
                #pragma unroll
                for (int r = 0; r < 4; ++r) {
                    int m = m_blk + wm + i * 16 + fq * 4 + r;
                    size_t off = (size_t)m * N + n;
                    Ob[off] = acc[i][j][r] + Xb[off];
                }
            }
    }
}

// ---- fused depthwise 5x5 (pad 2) + grouped pointwise (8->8), v7 ----
// packed-bf16 dot2 with edge words fetched by CROSS-LANE SHUFFLE:
// lo word (cols 8sx-2,-1) == lane-1's mid.w, hi word == lane+1's mid.x.
// 40 VMEM instr/thread; boundary lanes masked by lo_keep/hi_keep.
__global__ __launch_bounds__(256) void dwpw_kernel(
    const bf16* __restrict__ qkv, const float* __restrict__ w_dw,
    const float* __restrict__ w_pw, bf16* __restrict__ agg)
{
    const int bg = blockIdx.y;           // b*192 + g
    const int b = bg / 192;
    const int g = bg - b * 192;
    const int y0 = blockIdx.x * 32;      // output rows [y0, y0+32)

    __shared__ unsigned s_wdwp[8][16];   // packed bf16 weight pairs
    __shared__ float s_wpw[8][8];

    const int tid = threadIdx.x;

    // pack dw weights: per (c, i, part): pair (w[i*5+2p], w[i*5+2p+1]) ; part2 = (w4, 0)
    if (tid < 120) {
        int c = tid / 15, s = tid - c * 15;
        int i = s / 3, p = s - i * 3;
        int idx = i * 5 + p * 2;
        float w0 = w_dw[(size_t)(g * 8 + c) * 25 + idx];
        float w1 = (p < 2) ? w_dw[(size_t)(g * 8 + c) * 25 + idx + 1] : 0.f;
        unsigned u0 = __builtin_bit_cast(unsigned short, f2b(w0));
        unsigned u1 = __builtin_bit_cast(unsigned short, f2b(w1));
        s_wdwp[c][s] = u0 | (u1 << 16);
    }
    if (tid < 64)
        s_wpw[tid >> 3][tid & 7] = w_pw[(size_t)(g * 8 + (tid >> 3)) * 8 + (tid & 7)];
    __syncthreads();

    const int py = tid >> 3;             // 0..31
    const int sx = tid & 7;              // 0..7 (8-col strip)
    const int yq = y0 + py;
    const size_t chan_base = ((size_t)b * 1536 + g * 8) * 4096;

    const unsigned lo_keep = (sx > 0) ? 0xFFFFFFFFu : 0u;
    const unsigned hi_keep = (sx < 7) ? 0xFFFFFFFFu : 0u;

    float dwv[8][8];
    #pragma unroll
    for (int c = 0; c < 8; ++c) {
        unsigned wpq[16];
        #pragma unroll
        for (int q = 0; q < 4; ++q)
            *(uint4*)&wpq[q * 4] = *(const uint4*)&s_wdwp[c][q * 4];

        const char* cbase = (const char*)(qkv + chan_base + (size_t)c * 4096);
        float a[8] = {};
        #pragma unroll
        for (int i = 0; i < 5; ++i) {
            const int y = yq + i - 2;
            const bool row_ok = ((unsigned)y < 64u);
            const int yc = row_ok ? y : 0;             // safe address
            const char* rowp = cbase + yc * 128;       // 128 B per row
            uint4 mid = *(const uint4*)(rowp + 16 * sx);
            const unsigned m = row_ok ? 0xFFFFFFFFu : 0u;

            // edge words from neighbor lanes' registers (same py, same y)
            unsigned lo = (unsigned)__shfl_up((int)mid.w, 1, 64);
            unsigned hi = (unsigned)__shfl_down((int)mid.x, 1, 64);

            // packed bf16 words W0..W5 = elems (e0,e1)..(e10,e11), e_k = col 8sx-2+k
            unsigned W0 = lo & m & lo_keep;
            unsigned W1 = mid.x & m, W2 = mid.y & m;
            unsigned W3 = mid.z & m, W4 = mid.w & m;
            unsigned W5 = hi & m & hi_keep;
            // shifted pairs S_k = (e_{2k+1}, e_{2k+2})
            unsigned S0 = __builtin_amdgcn_alignbit(W1, W0, 16);
            unsigned S1 = __builtin_amdgcn_alignbit(W2, W1, 16);
            unsigned S2 = __builtin_amdgcn_alignbit(W3, W2, 16);
            unsigned S3 = __builtin_amdgcn_alignbit(W4, W3, 16);
            unsigned S4 = __builtin_amdgcn_alignbit(W5, W4, 16);
            unsigned S5 = W5 >> 16;                    // (e11, 0)

            unsigned w01 = wpq[i * 3], w23 = wpq[i * 3 + 1], w4z = wpq[i * 3 + 2];
            // even x: pairs W[x/2], W[x/2+1], W[x/2+2]
            a[0] = dot2bf(W0, w01, dot2bf(W1, w23, dot2bf(W2, w4z, a[0])));
            a[2] = dot2bf(W1, w01, dot2bf(W2, w23, dot2bf(W3, w4z, a[2])));
            a[4] = dot2bf(W2, w01, dot2bf(W3, w23, dot2bf(W4, w4z, a[4])));
            a[6] = dot2bf(W3, w01, dot2bf(W4, w23, dot2bf(W5, w4z, a[6])));
            // odd x: pairs S[(x-1)/2], S[(x+1)/2], S[(x+3)/2]
            a[1] = dot2bf(S0, w01, dot2bf(S1, w23, dot2bf(S2, w4z, a[1])));
            a[3] = dot2bf(S1, w01, dot2bf(S2, w23, dot2bf(S3, w4z, a[3])));
            a[5] = dot2bf(S2, w01, dot2bf(S3, w23, dot2bf(S4, w4z, a[5])));
            a[7] = dot2bf(S3, w01, dot2bf(S4, w23, dot2bf(S5, w4z, a[7])));
        }
        #pragma unroll
        for (int x = 0; x < 8; ++x) dwv[c][x] = a[x];
    }

    // grouped pointwise 8->8 + bf16 pack/store (16B per channel, coalesced)
    const size_t out_pix = (size_t)yq * 64 + 8 * sx;
    #pragma unroll
    for (int o = 0; o < 8; ++o) {
        float wv[8];
        *(float4*)&wv[0] = *(const float4*)&s_wpw[o][0];
        *(float4*)&wv[4] = *(const float4*)&s_wpw[o][4];
        float s[8] = {};
        #pragma unroll
        for (int i = 0; i < 8; ++i)
            #pragma unroll
            for (int x = 0; x < 8; ++x) s[x] += dwv[i][x] * wv[i];
        union { bf16 hv[8]; uint4 u; } pk;
        #pragma unroll
        for (int x = 0; x < 8; ++x) pk.hv[x] = f2b(s[x]);
        *(uint4*)(agg + chan_base + (size_t)o * 4096 + out_pix) = pk.u;
    }
}

// ---- vk[bh,d,e] = sum_n v[d,n]*relu(k[e,n]); row d=8 = sum relu(k) ----
// v2: 512-thr blocks, one 8-n chunk per thread, short8 (16B) loads:
// 32 vector loads/thread vs 256 scalar 2B loads (G13).
__global__ __launch_bounds__(512) void vk_kernel(
    const bf16* __restrict__ qkv, const bf16* __restrict__ agg,
    float* __restrict__ vk)
{
    const int bh = blockIdx.x;   // 0..511
    const int b = bh >> 7;
    const int h = bh & 127;
    const bf16* base = (h < 64)
        ? (qkv + ((size_t)b * 1536 + h * 24) * 4096)
        : (agg + ((size_t)b * 1536 + (h - 64) * 24) * 4096);

    const int tid = threadIdx.x;
    const int n0 = tid * 8;      // 512 threads x 8 = 4096

    short8 kr[8], vr[8];
    #pragma unroll
    for (int e = 0; e < 8; ++e)
        kr[e] = *(const short8*)&base[(size_t)(8 + e) * 4096 + n0];
    #pragma unroll
    for (int d = 0; d < 8; ++d)
        vr[d] = *(const short8*)&base[(size_t)(16 + d) * 4096 + n0];

    float acc[9][8] = {};
    #pragma unroll
    for (int t = 0; t < 8; ++t) {
        float kt[8], vt[8];
        #pragma unroll
        for (int e = 0; e < 8; ++e)
            kt[e] = fmaxf(us2f((unsigned short)kr[e][t]), 0.f);
        #pragma unroll
        for (int d = 0; d < 8; ++d)
            vt[d] = us2f((unsigned short)vr[d][t]);
        #pragma unroll
        for (int d = 0; d < 8; ++d)
            #pragma unroll
            for (int e = 0; e < 8; ++e)
                acc[d][e] += vt[d] * kt[e];
        #pragma unroll
        for (int e = 0; e < 8; ++e) acc[8][e] += kt[e];
    }

    __shared__ float red[8][72];
    const int lane = tid & 63, wave = tid >> 6;
    #pragma unroll
    for (int d = 0; d < 9; ++d) {
        #pragma unroll
        for (int e = 0; e < 8; ++e) {
            float v = acc[d][e];
            #pragma unroll
            for (int off = 32; off > 0; off >>= 1) v += __shfl_down(v, off, 64);
            if (lane == 0) red[wave][d * 8 + e] = v;
        }
    }
    __syncthreads();
    if (tid < 72) {
        float v = 0.f;
        #pragma unroll
        for (int w = 0; w < 8; ++w) v += red[w][tid];
        vk[(size_t)bh * 72 + tid] = v;
    }
}

// ---- attn: head-chunk-transposed write over dead v-rows ----
// v2: 8-n chunk per thread, short8 q loads (8 x 16B vs 64 x 2B).
// chunk(b,h)[n][d] at (base + 16*4096) + n*8 + d
__global__ __launch_bounds__(256) void attn_out_kernel(
    bf16* __restrict__ qkv, bf16* __restrict__ agg,
    const float* __restrict__ vk)
{
    const int b = blockIdx.z;
    const int h = blockIdx.y;
    const int n0 = (blockIdx.x * 256 + threadIdx.x) * 8;
    bf16* base = (h < 64)
        ? (qkv + ((size_t)b * 1536 + h * 24) * 4096)
        : (agg + ((size_t)b * 1536 + (h - 64) * 24) * 4096);

    __shared__ float s_vk[72];
    if (threadIdx.x < 72)
        s_vk[threadIdx.x] = vk[((size_t)b * 128 + h) * 72 + threadIdx.x];
    __syncthreads();

    short8 qr[8];
    #pragma unroll
    for (int e = 0; e < 8; ++e)
        qr[e] = *(const short8*)&base[(size_t)e * 4096 + n0];

    char* outp = (char*)(base + (size_t)16 * 4096) + (size_t)n0 * 16;
    #pragma unroll
    for (int t = 0; t < 8; ++t) {
        float q[8];
        #pragma unroll
        for (int e = 0; e < 8; ++e)
            q[e] = fmaxf(us2f((unsigned short)qr[e][t]), 0.f);

        float o[9];
        #pragma unroll
        for (int d = 0; d < 9; ++d) {
            float s = 0.f;
            #pragma unroll
            for (int e = 0; e < 8; ++e) s += s_vk[d * 8 + e] * q[e];
            o[d] = s;
        }
        const float denom = o[8] + 1e-15f;

        union { bf16 hv[8]; uint4 u; } pk;
        #pragma unroll
        for (int d = 0; d < 8; ++d) pk.hv[d] = f2b(o[d] / denom);
        *(uint4*)(outp + (size_t)t * 16) = pk.u;
    }
}

extern "C" void kernel_launch(void* const* d_in, const int* in_sizes, int n_in,
                              void* d_out, int out_size, void* d_ws, size_t ws_size,
                              hipStream_t stream) {
    const float* x      = (const float*)d_in[0];
    const float* w_qkv  = (const float*)d_in[1];
    const float* w_dw   = (const float*)d_in[2];
    const float* w_pw   = (const float*)d_in[3];
    const float* w_proj = (const float*)d_in[4];

    char* ws = (char*)d_ws;
    bf16* w_qkv_bf  = (bf16*)ws;                               // 1,572,864 B
    bf16* w_proj_bf = (bf16*)(ws + 1572864);                   // 1,048,576 B
    float* vkbf     = (float*)(ws + 1572864 + 1048576);        //   147,456 B
    bf16* x_t       = (bf16*)(ws + 1572864 + 1048576 + 147456);          // 16 MiB
    bf16* qkv       = x_t + (size_t)4 * 4096 * 512;            // 48 MiB
    bf16* agg       = qkv + (size_t)4 * 1536 * 4096;           // 48 MiB

    // 0. weight conversion + x transpose
    convert_kernel<<<3072, 256, 0, stream>>>(w_qkv, w_qkv_bf, 786432);
    convert_kernel<<<2048, 256, 0, stream>>>(w_proj, w_proj_bf, 524288);
    transpose_x_kernel<<<dim3(128, 16, 4), 256, 0, stream>>>(x, x_t);

    // 1. qkv = w_qkv (1536x512) @ x[b]  (v11: NBUF=2, D=1)
    mfma_gemm_kernel<false><<<dim3(32, 12, 4), 256, 0, stream>>>(
        w_qkv_bf, x_t, nullptr, nullptr, qkv, 1536, 512);

    // 2. agg = grouped-PW(DW5x5(qkv)) — shfl-edge dot2 v7
    dwpw_kernel<<<dim3(2, 768), 256, 0, stream>>>(qkv, w_dw, w_pw, agg);

    // 3. vk per (b, head) — vectorized v2
    vk_kernel<<<dim3(512), 512, 0, stream>>>(qkv, agg, vkbf);

    // 4. attn (normalized), head-chunk-transposed — vectorized v2
    attn_out_kernel<<<dim3(2, 128, 4), 256, 0, stream>>>(qkv, agg, vkbf);

    // 5. out = x + w_proj (512x1024) @ attn[b]  (v11: NBUF=4, D=2)
    mfma_gemm_kernel<true><<<dim3(32, 4, 4), 256, 0, stream>>>(
        w_proj_bf, qkv, agg, x, d_out, 512, 1024);
}

// Round 17
// 237.999 us; speedup vs baseline: 1.0867x; 1.0524x over previous
//
#include <hip/hip_runtime.h>
#include <hip/hip_bf16.h>
#include <cstdint>
#include <cstddef>

// Shapes (fixed): B=4, C=512, H=W=64, N=4096, td=512. Inputs/outputs fp32
// (proven in R4). Compute in bf16 MFMA with fp32 accumulation.
//   x (4,512,4096) | w_qkv (1536,512) | w_dw (1536,25) | w_pw (1536,8) |
//   w_proj (512,1024) | out (4,512,4096) fp32
//
// ws layout (bytes; total ~114.6 MiB):
//   w_qkv_bf  1,572,864 | w_proj_bf 1,048,576 | vk 147,456 |
//   x_t (4,4096,512) bf16 16,777,216 | qkv 50,331,648 | agg 50,331,648
//
// attn is stored head-chunk-transposed over the dead v-rows of qkv/agg:
// chunk(b,h) = 4096 n x 8 d, d contiguous -> proj GEMM B^T staging is
// lane-contiguous for global_load_lds.

typedef __hip_bfloat16 bf16;
typedef __attribute__((ext_vector_type(8))) short short8;
typedef __attribute__((ext_vector_type(4))) float f32x4;

__device__ __forceinline__ float b2f(bf16 v) { return __bfloat162float(v); }
__device__ __forceinline__ bf16 f2b(float v) { return __float2bfloat16(v); }
__device__ __forceinline__ float us2f(unsigned short u) {
    return __uint_as_float(((unsigned)u) << 16);
}

// bf16-pair dot: acc += p.lo*w.lo + p.hi*w.hi (f32 accumulate).
// VOP3P v_dot2_f32_bf16 when available; scalar fallback otherwise.
__device__ __forceinline__ float dot2bf(unsigned p, unsigned wp, float acc) {
#if __has_builtin(__builtin_amdgcn_fdot2_f32_bf16)
    typedef __attribute__((ext_vector_type(2))) __bf16 bf16x2;
    return __builtin_amdgcn_fdot2_f32_bf16(
        __builtin_bit_cast(bf16x2, p), __builtin_bit_cast(bf16x2, wp),
        acc, false);
#else
    return acc
        + us2f((unsigned short)(p & 0xffffu))  * us2f((unsigned short)(wp & 0xffffu))
        + us2f((unsigned short)(p >> 16))      * us2f((unsigned short)(wp >> 16));
#endif
}

__device__ __forceinline__ void async16(void* lds_base, const void* gaddr) {
    // dest = lds_base (wave-uniform) + lane*16; per-lane global address.
    __builtin_amdgcn_global_load_lds(
        (const __attribute__((address_space(1))) unsigned int*)gaddr,
        (__attribute__((address_space(3))) unsigned int*)lds_base,
        16, 0, 0);
}

// ---- weight fp32 -> bf16 ----
__global__ __launch_bounds__(256) void convert_kernel(
    const float* __restrict__ src, bf16* __restrict__ dst, int n)
{
    int i = blockIdx.x * 256 + threadIdx.x;
    if (i < n) dst[i] = f2b(src[i]);
}

// ---- x (4,512,4096) fp32 -> x_t (4,4096,512) bf16 ----
__global__ __launch_bounds__(256) void transpose_x_kernel(
    const float* __restrict__ x, bf16* __restrict__ x_t)
{
    __shared__ bf16 tile[32][33];
    const int b = blockIdx.z;
    const int c0 = blockIdx.y * 32;
    const int n0 = blockIdx.x * 32;
    const int tx = threadIdx.x & 31, ty = threadIdx.x >> 5;  // 32x8
    #pragma unroll
    for (int i = 0; i < 32; i += 8)
        tile[ty + i][tx] = f2b(x[((size_t)b * 512 + c0 + ty + i) * 4096 + n0 + tx]);
    __syncthreads();
    #pragma unroll
    for (int i = 0; i < 32; i += 8)
        x_t[((size_t)b * 4096 + n0 + ty + i) * 512 + c0 + tx] = tile[tx][ty + i];
}

// ---- MFMA GEMM v12: v11 k-loop + LDS-transposed VECTOR epilogue ----
// R16 null: counted-vmcnt D=2 == drain D=1 (both 43.5) -> load-wait is
// NOT the bottleneck. Remaining violation: epilogue did 64 SCALAR
// stores/thread (qkv bf16 2B; proj f32 + 64 scalar X loads) ~7-10 us
// per GEMM of TA-serialized traffic. v12: each wave round-trips its
// 64x64 f32 tile through its own LDS zone (stride-68 rows -> 16B-aligned
// b128 reads) in 4 chunks of 16 rows; stores become 16B vectors:
// qkv 8x short8/thread, proj 16x float4 load+store.
// PROJ=false: C[b](1536x4096) bf16 = A(1536x512) * x_t[b]^T ; K=512
// PROJ=true:  out[b](512x4096) f32 = A(512x1024) * attn[b] + x[b] ; K=1024
template <bool PROJ>
__global__ __launch_bounds__(256) void mfma_gemm_kernel(
    const bf16* __restrict__ A, const bf16* __restrict__ xt_or_qkv,
    const bf16* __restrict__ agg, const float* __restrict__ X,
    void* __restrict__ Cout, int M, int K)
{
    constexpr int N = 4096;
    constexpr int NBUF = PROJ ? 4 : 2;   // proj: 64 KB LDS (grid-capped 2/CU)
    constexpr int D    = PROJ ? 2 : 1;   // prefetch distance
    const int b = blockIdx.z;
    const int m_blk = blockIdx.y * 128;
    const int n_blk = blockIdx.x * 128;

    // unified staging block: As[buf] = smem + buf*4096, Bs[buf] = +(NBUF+buf)*4096
    __shared__ short smem[NBUF * 2 * 128 * 32];

    const int tid = threadIdx.x;
    const int lane = tid & 63, wave = tid >> 6;
    const int wm = (wave >> 1) * 64, wn = (wave & 1) * 64;
    const int fm = lane & 15, fq = lane >> 4;

    f32x4 acc[4][4] = {};

    const short* Ag = (const short*)A;
    const short* Btg = PROJ ? nullptr
        : (const short*)(xt_or_qkv + (size_t)b * N * 512);  // x_t[b]

    // stage one 32-k tile into buffer `buf` (4 async16 per wave)
    auto stage = [&](int buf, int k0) {
        short* Asb = &smem[buf * 4096];
        short* Bsb = &smem[(NBUF + buf) * 4096];
        #pragma unroll
        for (int t0 = 0; t0 < 2; ++t0) {
            int t = wave + t0 * 4;
            int row = m_blk + t * 16 + (lane >> 2);
            int col = k0 + (lane & 3) * 8;
            async16(&Asb[t * 512], Ag + (size_t)row * K + col);
        }
        #pragma unroll
        for (int t0 = 0; t0 < 2; ++t0) {
            int t = wave + t0 * 4;
            int n = n_blk + t * 16 + (lane >> 2);
            if (!PROJ) {
                int col = k0 + (lane & 3) * 8;
                async16(&Bsb[t * 512], Btg + (size_t)n * 512 + col);
            } else {
                int h = (k0 >> 3) + (lane & 3);      // 4 heads per k-tile
                const bf16* chunk = (h < 64 ? xt_or_qkv : agg) +
                    ((size_t)b * 1536 + (size_t)(h & 63) * 24 + 16) * 4096;
                async16(&Bsb[t * 512], chunk + (size_t)n * 8);
            }
        }
    };

    const int nt = K >> 5;
    stage(0, 0);
    if (D == 2 && nt > 1) stage(1, 32);

    for (int t = 0; t < nt; ++t) {
        // drain tile t's 4 loads; with D=2 leave tile t+1's 4 in flight
        if (D == 2 && t < nt - 1)
            asm volatile("s_waitcnt vmcnt(4)" ::: "memory");
        else
            asm volatile("s_waitcnt vmcnt(0)" ::: "memory");
        __builtin_amdgcn_s_barrier();    // buf[t % NBUF] ready for all waves
        if (t + D < nt) stage((t + D) & (NBUF - 1), (t + D) * 32);

        const int cb = t & (NBUF - 1);
        const short* Asb = &smem[cb * 4096];
        const short* Bsb = &smem[(NBUF + cb) * 4096];
        short8 af[4], bfv[4];
        #pragma unroll
        for (int i = 0; i < 4; ++i)
            af[i] = *(const short8*)&Asb[(wm + i * 16 + fm) * 32 + fq * 8];
        #pragma unroll
        for (int j = 0; j < 4; ++j)
            bfv[j] = *(const short8*)&Bsb[(wn + j * 16 + fm) * 32 + fq * 8];
        #pragma unroll
        for (int i = 0; i < 4; ++i)
            #pragma unroll
            for (int j = 0; j < 4; ++j)
                acc[i][j] = __builtin_amdgcn_mfma_f32_16x16x32_bf16(
                    af[i], bfv[j], acc[i][j], 0, 0, 0);
    }

    // ---- vector epilogue via per-wave LDS zone (stride 68 = 16B rows) ----
    __syncthreads();   // k-loop LDS reads done in ALL waves before overwrite
    float* zone = (float*)smem + wave * 1088;   // 16 rows x 68, 4352 B/wave
    bf16* Cb  = PROJ ? nullptr : (bf16*)Cout + (size_t)b * M * N;
    float* Ob = PROJ ? (float*)Cout + (size_t)b * M * N : nullptr;
    const float* Xb = PROJ ? X + (size_t)b * M * N : nullptr;

    #pragma unroll
    for (int i = 0; i < 4; ++i) {
        // scatter fragments: acc[i][j][r] -> zone[(fq*4+r)*68 + j*16+fm]
        #pragma unroll
        for (int j = 0; j < 4; ++j)
            #pragma unroll
            for (int r = 0; r < 4; ++r)
                zone[(fq * 4 + r) * 68 + j * 16 + fm] = acc[i][j][r];
        __syncthreads();   // write->read fence (and lgkm drain)

        #pragma unroll
        for (int p = 0; p < 2; ++p) {
            int idx = p * 64 + lane;
            int row = idx >> 3;              // 0..15
            int c0 = (idx & 7) * 8;          // 0..56
            f32x4 v0 = *(const f32x4*)&zone[row * 68 + c0];
            f32x4 v1 = *(const f32x4*)&zone[row * 68 + c0 + 4];
            int m = m_blk + wm + i * 16 + row;
            size_t off = (size_t)m * N + n_blk + wn + c0;
            if (!PROJ) {
                union { bf16 hv[8]; uint4 u; } pk;
                #pragma unroll
                for (int d = 0; d < 4; ++d) {
                    pk.hv[d] = f2b(v0[d]);
                    pk.hv[4 + d] = f2b(v1[d]);
                }
                *(uint4*)&Cb[off] = pk.u;
            } else {
                f32x4 x0 = *(const f32x4*)&Xb[off];
                f32x4 x1 = *(const f32x4*)&Xb[off + 4];
                *(f32x4*)&Ob[off]     = v0 + x0;
                *(f32x4*)&Ob[off + 4] = v1 + x1;
            }
        }
        __syncthreads();   // reads done before next chunk's writes
    }
}

// ---- fused depthwise 5x5 (pad 2) + grouped pointwise (8->8), v7 ----
// packed-bf16 dot2 with edge words fetched by CROSS-LANE SHUFFLE:
// lo word (cols 8sx-2,-1) == lane-1's mid.w, hi word == lane+1's mid.x.
// 40 VMEM instr/thread; boundary lanes masked by lo_keep/hi_keep.
__global__ __launch_bounds__(256) void dwpw_kernel(
    const bf16* __restrict__ qkv, const float* __restrict__ w_dw,
    const float* __restrict__ w_pw, bf16* __restrict__ agg)
{
    const int bg = blockIdx.y;           // b*192 + g
    const int b = bg / 192;
    const int g = bg - b * 192;
    const int y0 = blockIdx.x * 32;      // output rows [y0, y0+32)

    __shared__ unsigned s_wdwp[8][16];   // packed bf16 weight pairs
    __shared__ float s_wpw[8][8];

    const int tid = threadIdx.x;

    // pack dw weights: per (c, i, part): pair (w[i*5+2p], w[i*5+2p+1]) ; part2 = (w4, 0)
    if (tid < 120) {
        int c = tid / 15, s = tid - c * 15;
        int i = s / 3, p = s - i * 3;
        int idx = i * 5 + p * 2;
        float w0 = w_dw[(size_t)(g * 8 + c) * 25 + idx];
        float w1 = (p < 2) ? w_dw[(size_t)(g * 8 + c) * 25 + idx + 1] : 0.f;
        unsigned u0 = __builtin_bit_cast(unsigned short, f2b(w0));
        unsigned u1 = __builtin_bit_cast(unsigned short, f2b(w1));
        s_wdwp[c][s] = u0 | (u1 << 16);
    }
    if (tid < 64)
        s_wpw[tid >> 3][tid & 7] = w_pw[(size_t)(g * 8 + (tid >> 3)) * 8 + (tid & 7)];
    __syncthreads();

    const int py = tid >> 3;             // 0..31
    const int sx = tid & 7;              // 0..7 (8-col strip)
    const int yq = y0 + py;
    const size_t chan_base = ((size_t)b * 1536 + g * 8) * 4096;

    const unsigned lo_keep = (sx > 0) ? 0xFFFFFFFFu : 0u;
    const unsigned hi_keep = (sx < 7) ? 0xFFFFFFFFu : 0u;

    float dwv[8][8];
    #pragma unroll
    for (int c = 0; c < 8; ++c) {
        unsigned wpq[16];
        #pragma unroll
        for (int q = 0; q < 4; ++q)
            *(uint4*)&wpq[q * 4] = *(const uint4*)&s_wdwp[c][q * 4];

        const char* cbase = (const char*)(qkv + chan_base + (size_t)c * 4096);
        float a[8] = {};
        #pragma unroll
        for (int i = 0; i < 5; ++i) {
            const int y = yq + i - 2;
            const bool row_ok = ((unsigned)y < 64u);
            const int yc = row_ok ? y : 0;             // safe address
            const char* rowp = cbase + yc * 128;       // 128 B per row
            uint4 mid = *(const uint4*)(rowp + 16 * sx);
            const unsigned m = row_ok ? 0xFFFFFFFFu : 0u;

            // edge words from neighbor lanes' registers (same py, same y)
            unsigned lo = (unsigned)__shfl_up((int)mid.w, 1, 64);
            unsigned hi = (unsigned)__shfl_down((int)mid.x, 1, 64);

            // packed bf16 words W0..W5 = elems (e0,e1)..(e10,e11), e_k = col 8sx-2+k
            unsigned W0 = lo & m & lo_keep;
            unsigned W1 = mid.x & m, W2 = mid.y & m;
            unsigned W3 = mid.z & m, W4 = mid.w & m;
            unsigned W5 = hi & m & hi_keep;
            // shifted pairs S_k = (e_{2k+1}, e_{2k+2})
            unsigned S0 = __builtin_amdgcn_alignbit(W1, W0, 16);
            unsigned S1 = __builtin_amdgcn_alignbit(W2, W1, 16);
            unsigned S2 = __builtin_amdgcn_alignbit(W3, W2, 16);
            unsigned S3 = __builtin_amdgcn_alignbit(W4, W3, 16);
            unsigned S4 = __builtin_amdgcn_alignbit(W5, W4, 16);
            unsigned S5 = W5 >> 16;                    // (e11, 0)

            unsigned w01 = wpq[i * 3], w23 = wpq[i * 3 + 1], w4z = wpq[i * 3 + 2];
            // even x: pairs W[x/2], W[x/2+1], W[x/2+2]
            a[0] = dot2bf(W0, w01, dot2bf(W1, w23, dot2bf(W2, w4z, a[0])));
            a[2] = dot2bf(W1, w01, dot2bf(W2, w23, dot2bf(W3, w4z, a[2])));
            a[4] = dot2bf(W2, w01, dot2bf(W3, w23, dot2bf(W4, w4z, a[4])));
            a[6] = dot2bf(W3, w01, dot2bf(W4, w23, dot2bf(W5, w4z, a[6])));
            // odd x: pairs S[(x-1)/2], S[(x+1)/2], S[(x+3)/2]
            a[1] = dot2bf(S0, w01, dot2bf(S1, w23, dot2bf(S2, w4z, a[1])));
            a[3] = dot2bf(S1, w01, dot2bf(S2, w23, dot2bf(S3, w4z, a[3])));
            a[5] = dot2bf(S2, w01, dot2bf(S3, w23, dot2bf(S4, w4z, a[5])));
            a[7] = dot2bf(S3, w01, dot2bf(S4, w23, dot2bf(S5, w4z, a[7])));
        }
        #pragma unroll
        for (int x = 0; x < 8; ++x) dwv[c][x] = a[x];
    }

    // grouped pointwise 8->8 + bf16 pack/store (16B per channel, coalesced)
    const size_t out_pix = (size_t)yq * 64 + 8 * sx;
    #pragma unroll
    for (int o = 0; o < 8; ++o) {
        float wv[8];
        *(float4*)&wv[0] = *(const float4*)&s_wpw[o][0];
        *(float4*)&wv[4] = *(const float4*)&s_wpw[o][4];
        float s[8] = {};
        #pragma unroll
        for (int i = 0; i < 8; ++i)
            #pragma unroll
            for (int x = 0; x < 8; ++x) s[x] += dwv[i][x] * wv[i];
        union { bf16 hv[8]; uint4 u; } pk;
        #pragma unroll
        for (int x = 0; x < 8; ++x) pk.hv[x] = f2b(s[x]);
        *(uint4*)(agg + chan_base + (size_t)o * 4096 + out_pix) = pk.u;
    }
}

// ---- vk[bh,d,e] = sum_n v[d,n]*relu(k[e,n]); row d=8 = sum relu(k) ----
// v2: 512-thr blocks, one 8-n chunk per thread, short8 (16B) loads:
// 32 vector loads/thread vs 256 scalar 2B loads (G13).
__global__ __launch_bounds__(512) void vk_kernel(
    const bf16* __restrict__ qkv, const bf16* __restrict__ agg,
    float* __restrict__ vk)
{
    const int bh = blockIdx.x;   // 0..511
    const int b = bh >> 7;
    const int h = bh & 127;
    const bf16* base = (h < 64)
        ? (qkv + ((size_t)b * 1536 + h * 24) * 4096)
        : (agg + ((size_t)b * 1536 + (h - 64) * 24) * 4096);

    const int tid = threadIdx.x;
    const int n0 = tid * 8;      // 512 threads x 8 = 4096

    short8 kr[8], vr[8];
    #pragma unroll
    for (int e = 0; e < 8; ++e)
        kr[e] = *(const short8*)&base[(size_t)(8 + e) * 4096 + n0];
    #pragma unroll
    for (int d = 0; d < 8; ++d)
        vr[d] = *(const short8*)&base[(size_t)(16 + d) * 4096 + n0];

    float acc[9][8] = {};
    #pragma unroll
    for (int t = 0; t < 8; ++t) {
        float kt[8], vt[8];
        #pragma unroll
        for (int e = 0; e < 8; ++e)
            kt[e] = fmaxf(us2f((unsigned short)kr[e][t]), 0.f);
        #pragma unroll
        for (int d = 0; d < 8; ++d)
            vt[d] = us2f((unsigned short)vr[d][t]);
        #pragma unroll
        for (int d = 0; d < 8; ++d)
            #pragma unroll
            for (int e = 0; e < 8; ++e)
                acc[d][e] += vt[d] * kt[e];
        #pragma unroll
        for (int e = 0; e < 8; ++e) acc[8][e] += kt[e];
    }

    __shared__ float red[8][72];
    const int lane = tid & 63, wave = tid >> 6;
    #pragma unroll
    for (int d = 0; d < 9; ++d) {
        #pragma unroll
        for (int e = 0; e < 8; ++e) {
            float v = acc[d][e];
            #pragma unroll
            for (int off = 32; off > 0; off >>= 1) v += __shfl_down(v, off, 64);
            if (lane == 0) red[wave][d * 8 + e] = v;
        }
    }
    __syncthreads();
    if (tid < 72) {
        float v = 0.f;
        #pragma unroll
        for (int w = 0; w < 8; ++w) v += red[w][tid];
        vk[(size_t)bh * 72 + tid] = v;
    }
}

// ---- attn: head-chunk-transposed write over dead v-rows ----
// v2: 8-n chunk per thread, short8 q loads (8 x 16B vs 64 x 2B).
// chunk(b,h)[n][d] at (base + 16*4096) + n*8 + d
__global__ __launch_bounds__(256) void attn_out_kernel(
    bf16* __restrict__ qkv, bf16* __restrict__ agg,
    const float* __restrict__ vk)
{
    const int b = blockIdx.z;
    const int h = blockIdx.y;
    const int n0 = (blockIdx.x * 256 + threadIdx.x) * 8;
    bf16* base = (h < 64)
        ? (qkv + ((size_t)b * 1536 + h * 24) * 4096)
        : (agg + ((size_t)b * 1536 + (h - 64) * 24) * 4096);

    __shared__ float s_vk[72];
    if (threadIdx.x < 72)
        s_vk[threadIdx.x] = vk[((size_t)b * 128 + h) * 72 + threadIdx.x];
    __syncthreads();

    short8 qr[8];
    #pragma unroll
    for (int e = 0; e < 8; ++e)
        qr[e] = *(const short8*)&base[(size_t)e * 4096 + n0];

    char* outp = (char*)(base + (size_t)16 * 4096) + (size_t)n0 * 16;
    #pragma unroll
    for (int t = 0; t < 8; ++t) {
        float q[8];
        #pragma unroll
        for (int e = 0; e < 8; ++e)
            q[e] = fmaxf(us2f((unsigned short)qr[e][t]), 0.f);

        float o[9];
        #pragma unroll
        for (int d = 0; d < 9; ++d) {
            float s = 0.f;
            #pragma unroll
            for (int e = 0; e < 8; ++e) s += s_vk[d * 8 + e] * q[e];
            o[d] = s;
        }
        const float denom = o[8] + 1e-15f;

        union { bf16 hv[8]; uint4 u; } pk;
        #pragma unroll
        for (int d = 0; d < 8; ++d) pk.hv[d] = f2b(o[d] / denom);
        *(uint4*)(outp + (size_t)t * 16) = pk.u;
    }
}

extern "C" void kernel_launch(void* const* d_in, const int* in_sizes, int n_in,
                              void* d_out, int out_size, void* d_ws, size_t ws_size,
                              hipStream_t stream) {
    const float* x      = (const float*)d_in[0];
    const float* w_qkv  = (const float*)d_in[1];
    const float* w_dw   = (const float*)d_in[2];
    const float* w_pw   = (const float*)d_in[3];
    const float* w_proj = (const float*)d_in[4];

    char* ws = (char*)d_ws;
    bf16* w_qkv_bf  = (bf16*)ws;                               // 1,572,864 B
    bf16* w_proj_bf = (bf16*)(ws + 1572864);                   // 1,048,576 B
    float* vkbf     = (float*)(ws + 1572864 + 1048576);        //   147,456 B
    bf16* x_t       = (bf16*)(ws + 1572864 + 1048576 + 147456);          // 16 MiB
    bf16* qkv       = x_t + (size_t)4 * 4096 * 512;            // 48 MiB
    bf16* agg       = qkv + (size_t)4 * 1536 * 4096;           // 48 MiB

    // 0. weight conversion + x transpose
    convert_kernel<<<3072, 256, 0, stream>>>(w_qkv, w_qkv_bf, 786432);
    convert_kernel<<<2048, 256, 0, stream>>>(w_proj, w_proj_bf, 524288);
    transpose_x_kernel<<<dim3(128, 16, 4), 256, 0, stream>>>(x, x_t);

    // 1. qkv = w_qkv (1536x512) @ x[b]  (v12: NBUF=2, D=1, vector epilogue)
    mfma_gemm_kernel<false><<<dim3(32, 12, 4), 256, 0, stream>>>(
        w_qkv_bf, x_t, nullptr, nullptr, qkv, 1536, 512);

    // 2. agg = grouped-PW(DW5x5(qkv)) — shfl-edge dot2 v7
    dwpw_kernel<<<dim3(2, 768), 256, 0, stream>>>(qkv, w_dw, w_pw, agg);

    // 3. vk per (b, head) — vectorized v2
    vk_kernel<<<dim3(512), 512, 0, stream>>>(qkv, agg, vkbf);

    // 4. attn (normalized), head-chunk-transposed — vectorized v2
    attn_out_kernel<<<dim3(2, 128, 4), 256, 0, stream>>>(qkv, agg, vkbf);

    // 5. out = x + w_proj (512x1024) @ attn[b]  (v12: NBUF=4, D=2, vector epilogue)
    mfma_gemm_kernel<true><<<dim3(32, 4, 4), 256, 0, stream>>>(
        w_proj_bf, qkv, agg, x, d_out, 512, 1024);
}